// Round 1
// baseline (286.183 us; speedup 1.0000x reference)
//
#include <hip/hip_runtime.h>
#include <math.h>

// Problem constants (fixed by the reference's setup_inputs)
constexpr int B = 16, A = 3, S = 80, C = 80, N = 32;
constexpr int CELLS = B * A * S * S;          // 307200
constexpr int CH = 5 + C;                      // 85 channels per anchor
constexpr float EPS = 1e-7f;
constexpr int BDIM = 256;

__device__ __forceinline__ float softplusf(float x) {
    // matches jax.nn.softplus = max(x,0) + log1p(exp(-|x|))
    return fmaxf(x, 0.0f) + log1pf(expf(-fabsf(x)));
}

// One thread per batch image; serial over targets => deterministic last-write-wins,
// matching numpy/XLA duplicate-scatter ordering. Writes packed (n<<8)|cls, -1 = no obj.
__global__ void yolo_scatter(const float* __restrict__ anchors,
                             const int* __restrict__ tcls,
                             const float* __restrict__ tbox,
                             int* __restrict__ cellinfo) {
    int b = threadIdx.x;
    if (b >= B) return;
    float aw[A], ah[A];
    for (int a = 0; a < A; a++) { aw[a] = anchors[a * 2]; ah[a] = anchors[a * 2 + 1]; }
    for (int n = 0; n < N; n++) {
        int idx = b * N + n;
        float x = tbox[idx * 4 + 0], y = tbox[idx * 4 + 1];
        float w = tbox[idx * 4 + 2], h = tbox[idx * 4 + 3];
        int gi = (int)floorf(x * (float)S); gi = min(max(gi, 0), S - 1);
        int gj = (int)floorf(y * (float)S); gj = min(max(gj, 0), S - 1);
        float tw = w * 640.0f, th = h * 640.0f;
        int best_a = 0; float best = -1.0f;
        for (int a = 0; a < A; a++) {            // first-max wins == jnp.argmax
            float inter = fminf(tw, aw[a]) * fminf(th, ah[a]);
            float uni = tw * th + aw[a] * ah[a] - inter;
            float r = inter / uni;
            if (r > best) { best = r; best_a = a; }
        }
        int cls = tcls[idx];
        cellinfo[((b * A + best_a) * S + gj) * S + gi] = (n << 8) | cls;
    }
}

__global__ void __launch_bounds__(BDIM) yolo_main(
        const float* __restrict__ preds,
        const float* __restrict__ anchors,
        const float* __restrict__ tbox,
        const int* __restrict__ cellinfo,
        double* __restrict__ acc,           // [s_ciou, s_obj, s_noobj, s_cls]
        unsigned int* __restrict__ cnt) {
    int t = blockIdx.x * BDIM + threadIdx.x;
    float s_ciou = 0.0f, s_obj = 0.0f, s_noobj = 0.0f, s_cls = 0.0f;
    unsigned int c_obj = 0;

    if (t < CELLS) {
        int i = t % S;
        int j = (t / S) % S;
        int a = (t / (S * S)) % A;
        int b = t / (S * S * A);
        int base = ((b * (A * CH) + a * CH) * S + j) * S + i;  // channel stride = S*S
        float conf = preds[base + 4 * S * S];
        float sp = softplusf(conf);
        int info = cellinfo[t];
        if (info >= 0) {
            c_obj = 1;
            s_obj = sp - conf;                 // bce(conf, 1)
            int n = info >> 8, cls = info & 255;
            // ---- class loss: sum_c softplus(l_c) - l_cls ----
            const float* cbase = preds + base + 5 * S * S;
            float scl = 0.0f, lcls = 0.0f;
            for (int c = 0; c < C; c++) {
                float l = cbase[c * S * S];
                scl += softplusf(l);
                if (c == cls) lcls = l;
            }
            s_cls = scl - lcls;
            // ---- CIoU ----
            float tx = preds[base + 0 * S * S];
            float ty = preds[base + 1 * S * S];
            float twl = preds[base + 2 * S * S];
            float thl = preds[base + 3 * S * S];
            float pcx = (1.0f / (1.0f + expf(-tx)) + (float)i) * 8.0f;
            float pcy = (1.0f / (1.0f + expf(-ty)) + (float)j) * 8.0f;
            float aw = anchors[a * 2], ah = anchors[a * 2 + 1];
            float pw = aw * expf(twl), ph = ah * expf(thl);
            float px1 = pcx - pw * 0.5f, px2 = pcx + pw * 0.5f;
            float py1 = pcy - ph * 0.5f, py2 = pcy + ph * 0.5f;
            int ti = (b * N + n) * 4;
            float cx = tbox[ti + 0] * 640.0f, cy = tbox[ti + 1] * 640.0f;
            float tw = tbox[ti + 2] * 640.0f, th = tbox[ti + 3] * 640.0f;
            float tx1 = cx - tw * 0.5f, tx2 = cx + tw * 0.5f;
            float ty1 = cy - th * 0.5f, ty2 = cy + th * 0.5f;
            float iw = fmaxf(fminf(px2, tx2) - fmaxf(px1, tx1), 0.0f);
            float ih = fmaxf(fminf(py2, ty2) - fmaxf(py1, ty1), 0.0f);
            float inter = iw * ih;
            float pa = fmaxf(px2 - px1, 0.0f) * fmaxf(py2 - py1, 0.0f);
            float ta = fmaxf(tx2 - tx1, 0.0f) * fmaxf(ty2 - ty1, 0.0f);
            float uni = pa + ta - inter + EPS;
            float iou = inter / uni;
            float dx = (px1 + px2) * 0.5f - (tx1 + tx2) * 0.5f;
            float dy = (py1 + py2) * 0.5f - (ty1 + ty2) * 0.5f;
            float cdist = dx * dx + dy * dy;
            float ew = fmaxf(px2, tx2) - fminf(px1, tx1);
            float eh = fmaxf(py2, ty2) - fminf(py1, ty1);
            float ediag = ew * ew + eh * eh + EPS;
            float pwc = fmaxf(px2 - px1, EPS), phc = fmaxf(py2 - py1, EPS);
            float twc = fmaxf(tx2 - tx1, EPS), thc = fmaxf(ty2 - ty1, EPS);
            float dv = atanf(twc / thc) - atanf(pwc / phc);
            float v = (float)(4.0 / (M_PI * M_PI)) * dv * dv;
            float alpha = v / (1.0f - iou + v + EPS);
            s_ciou = iou - cdist / ediag - alpha * v;
        } else {
            s_noobj = sp;                      // bce(conf, 0)
        }
    }

    // ---- block reduction: wave-64 shuffle, then LDS across 4 waves ----
    for (int off = 32; off > 0; off >>= 1) {
        s_ciou  += __shfl_down(s_ciou,  off);
        s_obj   += __shfl_down(s_obj,   off);
        s_noobj += __shfl_down(s_noobj, off);
        s_cls   += __shfl_down(s_cls,   off);
        c_obj   += __shfl_down(c_obj,   off);
    }
    __shared__ float sm[4][BDIM / 64];
    __shared__ unsigned int smc[BDIM / 64];
    int wave = threadIdx.x >> 6, lane = threadIdx.x & 63;
    if (lane == 0) {
        sm[0][wave] = s_ciou; sm[1][wave] = s_obj;
        sm[2][wave] = s_noobj; sm[3][wave] = s_cls;
        smc[wave] = c_obj;
    }
    __syncthreads();
    if (threadIdx.x == 0) {
        float t0 = 0, t1 = 0, t2 = 0, t3 = 0; unsigned int tc = 0;
        for (int w = 0; w < BDIM / 64; w++) {
            t0 += sm[0][w]; t1 += sm[1][w]; t2 += sm[2][w]; t3 += sm[3][w];
            tc += smc[w];
        }
        atomicAdd(&acc[0], (double)t0);
        atomicAdd(&acc[1], (double)t1);
        atomicAdd(&acc[2], (double)t2);
        atomicAdd(&acc[3], (double)t3);
        atomicAdd(cnt, tc);
    }
}

__global__ void yolo_finalize(const double* __restrict__ acc,
                              const unsigned int* __restrict__ cnt,
                              float* __restrict__ out) {
    double nobj = (double)(*cnt);
    double nno = (double)CELLS - nobj;
    double d_obj = fmax(nobj, 1.0);
    double d_no  = fmax(nno, 1.0);
    double d_cls = fmax(nobj * (double)C, 1.0);
    double loss = (1.0 - acc[0] / d_obj)
                + acc[1] / d_obj
                + 0.5 * (acc[2] / d_no)
                + acc[3] / d_cls;
    out[0] = (float)loss;
}

extern "C" void kernel_launch(void* const* d_in, const int* in_sizes, int n_in,
                              void* d_out, int out_size, void* d_ws, size_t ws_size,
                              hipStream_t stream) {
    const float* preds   = (const float*)d_in[0];
    const float* anchors = (const float*)d_in[1];
    const int*   tcls    = (const int*)d_in[2];
    const float* tbox    = (const float*)d_in[3];

    int* cellinfo = (int*)d_ws;
    char* accbase = (char*)d_ws + (size_t)CELLS * sizeof(int);
    double* acc = (double*)accbase;
    unsigned int* cnt = (unsigned int*)(accbase + 4 * sizeof(double));

    // ws is poisoned 0xAA before every timed launch — re-init every call.
    hipMemsetAsync(cellinfo, 0xFF, (size_t)CELLS * sizeof(int), stream);   // -1 sentinel
    hipMemsetAsync(accbase, 0, 4 * sizeof(double) + sizeof(unsigned int), stream);

    yolo_scatter<<<1, 64, 0, stream>>>(anchors, tcls, tbox, cellinfo);
    yolo_main<<<(CELLS + BDIM - 1) / BDIM, BDIM, 0, stream>>>(
        preds, anchors, tbox, cellinfo, acc, cnt);
    yolo_finalize<<<1, 1, 0, stream>>>(acc, cnt, (float*)d_out);
}

// Round 2
// 148.909 us; speedup vs baseline: 1.9219x; 1.9219x over previous
//
#include <hip/hip_runtime.h>
#include <math.h>

// Problem constants (fixed by the reference's setup_inputs)
constexpr int B = 16, A = 3, S = 80, C = 80, N = 32;
constexpr int CELLS = B * A * S * S;     // 307200
constexpr int CH = 5 + C;                // 85
constexpr int PLANE = S * S;             // 6400 floats per channel plane
constexpr float EPS = 1e-7f;

// ws layout
constexpr int N_DENSE_BLK = 300;         // 300 blocks * 256 thr * 4 floats = 307200 conf vals
constexpr size_t OBJ_OFF = 4096;         // bytes; double densePart[300] lives at 0
constexpr int NT = B * N;                // 512 targets, one wave each

__device__ __forceinline__ float softplusf(float x) {
    return fmaxf(x, 0.0f) + log1pf(expf(-fabsf(x)));
}

// target idx -> (gi, gj, best_a); identical math to reference
__device__ __forceinline__ void cell_of(const float* __restrict__ tbox,
                                        const float* aw, const float* ah,
                                        int idx, int& gi, int& gj, int& ba) {
    float x = tbox[idx * 4 + 0], y = tbox[idx * 4 + 1];
    float w = tbox[idx * 4 + 2], h = tbox[idx * 4 + 3];
    gi = min(max((int)floorf(x * (float)S), 0), S - 1);
    gj = min(max((int)floorf(y * (float)S), 0), S - 1);
    float tw = w * 640.0f, th = h * 640.0f;
    ba = 0; float best = -1.0f;
    #pragma unroll
    for (int a = 0; a < A; a++) {        // strict > : first-max wins == jnp.argmax
        float inter = fminf(tw, aw[a]) * fminf(th, ah[a]);
        float uni = tw * th + aw[a] * ah[a] - inter;
        float r = inter / uni;
        if (r > best) { best = r; ba = a; }
    }
}

// ---- dense: sum softplus(conf) over all 48 conf planes, branch-free ----
__global__ void __launch_bounds__(256) yolo_dense(const float* __restrict__ preds,
                                                  double* __restrict__ densePart) {
    int g = blockIdx.x * 256 + threadIdx.x;      // [0, 76800)
    int p = g / 1600;                            // plane id 0..47
    int r = g - p * 1600;                        // float4 within plane
    int b = p / 3, a = p - b * 3;
    const float4* src = (const float4*)preds;
    float4 v = src[(size_t)(b * (A * CH) + a * CH + 4) * (PLANE / 4) + r];
    float s = softplusf(v.x) + softplusf(v.y) + softplusf(v.z) + softplusf(v.w);
    #pragma unroll
    for (int off = 32; off > 0; off >>= 1) s += __shfl_down(s, off);
    __shared__ float sm[4];
    int wave = threadIdx.x >> 6, lane = threadIdx.x & 63;
    if (lane == 0) sm[wave] = s;
    __syncthreads();
    if (threadIdx.x == 0)
        densePart[blockIdx.x] = (double)(sm[0] + sm[1] + sm[2] + sm[3]);
}

// ---- sparse: one wave per target; winners compute ciou/obj/cls + noobj correction ----
__global__ void __launch_bounds__(256) yolo_obj(const float* __restrict__ preds,
                                                const float* __restrict__ anchors,
                                                const int* __restrict__ tcls,
                                                const float* __restrict__ tbox,
                                                float* __restrict__ objPart) {
    int wave = threadIdx.x >> 6, lane = threadIdx.x & 63;
    int t = blockIdx.x * 4 + wave;               // [0, 512)
    int b = t >> 5, n = t & 31;

    float aw[A], ah[A];
    #pragma unroll
    for (int a = 0; a < A; a++) { aw[a] = anchors[a * 2]; ah[a] = anchors[a * 2 + 1]; }

    int gi, gj, ba;
    cell_of(tbox, aw, ah, b * N + n, gi, gj, ba);

    // last-write-wins: n is the live writer iff no later n2 hits the same cell
    bool winner = true;
    for (int n2 = n + 1; n2 < N; n2++) {
        int gi2, gj2, ba2;
        cell_of(tbox, aw, ah, b * N + n2, gi2, gj2, ba2);
        if (gi2 == gi && gj2 == gj && ba2 == ba) { winner = false; break; }
    }

    float r_ciou = 0.f, r_obj = 0.f, r_corr = 0.f, r_cls = 0.f, r_cnt = 0.f;
    if (winner) {                                // wave-uniform branch
        int base = (b * (A * CH) + ba * CH) * PLANE + gj * S + gi;
        // class loss, lane-parallel: lane covers c=lane and c=lane+64
        int cls = tcls[b * N + n];
        float l0 = preds[base + (5 + lane) * PLANE];
        float scls = softplusf(l0) - ((lane == cls) ? l0 : 0.f);
        if (lane < C - 64) {
            float l1 = preds[base + (5 + 64 + lane) * PLANE];
            scls += softplusf(l1) - (((64 + lane) == cls) ? l1 : 0.f);
        }
        #pragma unroll
        for (int off = 32; off > 0; off >>= 1) scls += __shfl_down(scls, off);
        r_cls = scls;                            // valid in lane 0

        // box + conf (broadcast loads, computed redundantly on all lanes)
        float conf = preds[base + 4 * PLANE];
        float sp = softplusf(conf);
        r_obj = sp - conf;                       // bce(conf, 1)
        r_corr = sp;                             // remove from noobj sum
        r_cnt = 1.f;
        float tx = preds[base + 0 * PLANE], ty = preds[base + 1 * PLANE];
        float twl = preds[base + 2 * PLANE], thl = preds[base + 3 * PLANE];
        float pcx = (1.0f / (1.0f + expf(-tx)) + (float)gi) * 8.0f;
        float pcy = (1.0f / (1.0f + expf(-ty)) + (float)gj) * 8.0f;
        float pw = aw[ba] * expf(twl), ph = ah[ba] * expf(thl);
        float px1 = pcx - pw * 0.5f, px2 = pcx + pw * 0.5f;
        float py1 = pcy - ph * 0.5f, py2 = pcy + ph * 0.5f;
        int ti = (b * N + n) * 4;
        float cx = tbox[ti + 0] * 640.0f, cy = tbox[ti + 1] * 640.0f;
        float tw = tbox[ti + 2] * 640.0f, th = tbox[ti + 3] * 640.0f;
        float tx1 = cx - tw * 0.5f, tx2 = cx + tw * 0.5f;
        float ty1 = cy - th * 0.5f, ty2 = cy + th * 0.5f;
        float iw = fmaxf(fminf(px2, tx2) - fmaxf(px1, tx1), 0.0f);
        float ih = fmaxf(fminf(py2, ty2) - fmaxf(py1, ty1), 0.0f);
        float inter = iw * ih;
        float pa = fmaxf(px2 - px1, 0.0f) * fmaxf(py2 - py1, 0.0f);
        float ta = fmaxf(tx2 - tx1, 0.0f) * fmaxf(ty2 - ty1, 0.0f);
        float uni = pa + ta - inter + EPS;
        float iou = inter / uni;
        float dx = (px1 + px2) * 0.5f - (tx1 + tx2) * 0.5f;
        float dy = (py1 + py2) * 0.5f - (ty1 + ty2) * 0.5f;
        float cdist = dx * dx + dy * dy;
        float ew = fmaxf(px2, tx2) - fminf(px1, tx1);
        float eh = fmaxf(py2, ty2) - fminf(py1, ty1);
        float ediag = ew * ew + eh * eh + EPS;
        float pwc = fmaxf(px2 - px1, EPS), phc = fmaxf(py2 - py1, EPS);
        float twc = fmaxf(tx2 - tx1, EPS), thc = fmaxf(ty2 - ty1, EPS);
        float dv = atanf(twc / thc) - atanf(pwc / phc);
        float v = (float)(4.0 / (M_PI * M_PI)) * dv * dv;
        float alpha = v / (1.0f - iou + v + EPS);
        r_ciou = iou - cdist / ediag - alpha * v;
    }
    if (lane == 0) {                             // every wave writes its slot: no memset needed
        float* dst = objPart + (size_t)t * 8;
        dst[0] = r_ciou; dst[1] = r_obj; dst[2] = r_corr; dst[3] = r_cls; dst[4] = r_cnt;
    }
}

// ---- finalize: sum 300 dense partials + 512 obj partials, emit scalar loss ----
__global__ void __launch_bounds__(256) yolo_fin(const double* __restrict__ densePart,
                                                const float* __restrict__ objPart,
                                                float* __restrict__ out) {
    double sp = 0, ciou = 0, obj = 0, corr = 0, cls = 0, cnt = 0;
    for (int i = threadIdx.x; i < N_DENSE_BLK; i += 256) sp += densePart[i];
    for (int t = threadIdx.x; t < NT; t += 256) {
        const float* p = objPart + (size_t)t * 8;
        ciou += p[0]; obj += p[1]; corr += p[2]; cls += p[3]; cnt += p[4];
    }
    #pragma unroll
    for (int off = 32; off > 0; off >>= 1) {
        sp   += __shfl_down(sp, off);   ciou += __shfl_down(ciou, off);
        obj  += __shfl_down(obj, off);  corr += __shfl_down(corr, off);
        cls  += __shfl_down(cls, off);  cnt  += __shfl_down(cnt, off);
    }
    __shared__ double sm[6][4];
    int wave = threadIdx.x >> 6, lane = threadIdx.x & 63;
    if (lane == 0) {
        sm[0][wave] = sp;  sm[1][wave] = ciou; sm[2][wave] = obj;
        sm[3][wave] = corr; sm[4][wave] = cls; sm[5][wave] = cnt;
    }
    __syncthreads();
    if (threadIdx.x == 0) {
        double T[6];
        for (int k = 0; k < 6; k++) T[k] = sm[k][0] + sm[k][1] + sm[k][2] + sm[k][3];
        double nobj = T[5];
        double noobj_sum = T[0] - T[3];          // total softplus - obj cells' softplus
        double d_obj = fmax(nobj, 1.0);
        double d_no  = fmax((double)CELLS - nobj, 1.0);
        double d_cls = fmax(nobj * (double)C, 1.0);
        double loss = (1.0 - T[1] / d_obj) + T[2] / d_obj
                    + 0.5 * (noobj_sum / d_no) + T[4] / d_cls;
        out[0] = (float)loss;
    }
}

extern "C" void kernel_launch(void* const* d_in, const int* in_sizes, int n_in,
                              void* d_out, int out_size, void* d_ws, size_t ws_size,
                              hipStream_t stream) {
    const float* preds   = (const float*)d_in[0];
    const float* anchors = (const float*)d_in[1];
    const int*   tcls    = (const int*)d_in[2];
    const float* tbox    = (const float*)d_in[3];

    double* densePart = (double*)d_ws;                      // [300]
    float*  objPart   = (float*)((char*)d_ws + OBJ_OFF);    // [512*8]

    yolo_dense<<<N_DENSE_BLK, 256, 0, stream>>>(preds, densePart);
    yolo_obj<<<NT / 4, 256, 0, stream>>>(preds, anchors, tcls, tbox, objPart);
    yolo_fin<<<1, 256, 0, stream>>>(densePart, objPart, (float*)d_out);
}

// Round 3
// 140.251 us; speedup vs baseline: 2.0405x; 1.0617x over previous
//
#include <hip/hip_runtime.h>
#include <math.h>

// Problem constants (fixed by the reference's setup_inputs)
constexpr int B = 16, A = 3, S = 80, C = 80, N = 32;
constexpr int CELLS = B * A * S * S;     // 307200
constexpr int CH = 5 + C;                // 85
constexpr int PLANE = S * S;             // 6400 floats per channel plane
constexpr float EPS = 1e-7f;

constexpr int N_DENSE_BLK = 300;         // 300 blocks * 256 thr * 4 floats = 307200 conf vals
constexpr int NT = B * N;                // 512 targets, one wave each
constexpr int N_OBJ_BLK = NT / 4;        // 128
constexpr size_t OBJ_OFF = 4096;         // bytes; double densePart[300] at ws+0

__device__ __forceinline__ float softplusf(float x) {
    return fmaxf(x, 0.0f) + log1pf(expf(-fabsf(x)));
}

// ---- fused: blocks [0,300) dense conf sum; blocks [300,428) sparse obj ----
__global__ void __launch_bounds__(256) yolo_fused(const float* __restrict__ preds,
                                                  const float* __restrict__ anchors,
                                                  const int* __restrict__ tcls,
                                                  const float* __restrict__ tbox,
                                                  double* __restrict__ densePart,
                                                  float* __restrict__ objPart) {
    int wave = threadIdx.x >> 6, lane = threadIdx.x & 63;

    if (blockIdx.x < N_DENSE_BLK) {
        // ===== dense: sum softplus(conf) over all 48 conf planes, branch-free =====
        int g = blockIdx.x * 256 + threadIdx.x;      // [0, 76800)
        int p = g / 1600;                            // plane id 0..47
        int r = g - p * 1600;                        // float4 within plane
        int b = p / 3, a = p - b * 3;
        const float4* src = (const float4*)preds;
        float4 v = src[(size_t)(b * (A * CH) + a * CH + 4) * (PLANE / 4) + r];
        float s = softplusf(v.x) + softplusf(v.y) + softplusf(v.z) + softplusf(v.w);
        #pragma unroll
        for (int off = 32; off > 0; off >>= 1) s += __shfl_down(s, off);
        __shared__ float sm[4];
        if (lane == 0) sm[wave] = s;
        __syncthreads();
        if (threadIdx.x == 0)
            densePart[blockIdx.x] = (double)(sm[0] + sm[1] + sm[2] + sm[3]);
        return;
    }

    // ===== sparse: one wave per target =====
    int t = (blockIdx.x - N_DENSE_BLK) * 4 + wave;   // [0, 512)
    int b = t >> 5, n = t & 31;

    float aw[A], ah[A];
    #pragma unroll
    for (int a = 0; a < A; a++) { aw[a] = anchors[a * 2]; ah[a] = anchors[a * 2 + 1]; }

    // lanes 0..31: cell key for target (b, lane); identical math to reference
    int key = -1;
    if (lane < N) {
        float4 tb = ((const float4*)tbox)[b * N + lane];
        int gi = min(max((int)floorf(tb.x * (float)S), 0), S - 1);
        int gj = min(max((int)floorf(tb.y * (float)S), 0), S - 1);
        float tw = tb.z * 640.0f, th = tb.w * 640.0f;
        int ba = 0; float best = -1.0f;
        #pragma unroll
        for (int a = 0; a < A; a++) {                // strict > : first-max == jnp.argmax
            float inter = fminf(tw, aw[a]) * fminf(th, ah[a]);
            float uni = tw * th + aw[a] * ah[a] - inter;
            float r = inter / uni;
            if (r > best) { best = r; ba = a; }
        }
        key = (ba * S + gj) * S + gi;
    }
    int my_key = __shfl(key, n);
    unsigned long long eq = __ballot(key == my_key);
    // last-write-wins: winner iff no target n2 in (n, N) maps to the same cell
    bool winner = (eq & 0xFFFFFFFFull & ~((2ull << n) - 1ull)) == 0;

    float r_ciou = 0.f, r_obj = 0.f, r_corr = 0.f, r_cls = 0.f, r_cnt = 0.f;
    if (winner) {                                    // wave-uniform branch
        int ba = my_key / (S * S);
        int rem = my_key - ba * (S * S);
        int gj = rem / S, gi = rem - gj * S;
        int base = (b * (A * CH) + ba * CH) * PLANE + gj * S + gi;

        // class loss, lane-parallel: lane covers c=lane and c=lane+64
        int cls = tcls[b * N + n];
        float l0 = preds[base + (5 + lane) * PLANE];
        float scls = softplusf(l0) - ((lane == cls) ? l0 : 0.f);
        if (lane < C - 64) {
            float l1 = preds[base + (5 + 64 + lane) * PLANE];
            scls += softplusf(l1) - (((64 + lane) == cls) ? l1 : 0.f);
        }
        #pragma unroll
        for (int off = 32; off > 0; off >>= 1) scls += __shfl_down(scls, off);
        r_cls = scls;                                // valid in lane 0

        // box + conf (broadcast loads, computed redundantly on all lanes)
        float conf = preds[base + 4 * PLANE];
        float sp = softplusf(conf);
        r_obj = sp - conf;                           // bce(conf, 1)
        r_corr = sp;                                 // remove from noobj sum
        r_cnt = 1.f;
        float tx = preds[base + 0 * PLANE], ty = preds[base + 1 * PLANE];
        float twl = preds[base + 2 * PLANE], thl = preds[base + 3 * PLANE];
        float pcx = (1.0f / (1.0f + expf(-tx)) + (float)gi) * 8.0f;
        float pcy = (1.0f / (1.0f + expf(-ty)) + (float)gj) * 8.0f;
        float pw = aw[ba] * expf(twl), ph = ah[ba] * expf(thl);
        float px1 = pcx - pw * 0.5f, px2 = pcx + pw * 0.5f;
        float py1 = pcy - ph * 0.5f, py2 = pcy + ph * 0.5f;
        int ti = (b * N + n) * 4;
        float cx = tbox[ti + 0] * 640.0f, cy = tbox[ti + 1] * 640.0f;
        float tw = tbox[ti + 2] * 640.0f, th = tbox[ti + 3] * 640.0f;
        float tx1 = cx - tw * 0.5f, tx2 = cx + tw * 0.5f;
        float ty1 = cy - th * 0.5f, ty2 = cy + th * 0.5f;
        float iw = fmaxf(fminf(px2, tx2) - fmaxf(px1, tx1), 0.0f);
        float ih = fmaxf(fminf(py2, ty2) - fmaxf(py1, ty1), 0.0f);
        float inter = iw * ih;
        float pa = fmaxf(px2 - px1, 0.0f) * fmaxf(py2 - py1, 0.0f);
        float ta = fmaxf(tx2 - tx1, 0.0f) * fmaxf(ty2 - ty1, 0.0f);
        float uni = pa + ta - inter + EPS;
        float iou = inter / uni;
        float dx = (px1 + px2) * 0.5f - (tx1 + tx2) * 0.5f;
        float dy = (py1 + py2) * 0.5f - (ty1 + ty2) * 0.5f;
        float cdist = dx * dx + dy * dy;
        float ew = fmaxf(px2, tx2) - fminf(px1, tx1);
        float eh = fmaxf(py2, ty2) - fminf(py1, ty1);
        float ediag = ew * ew + eh * eh + EPS;
        float pwc = fmaxf(px2 - px1, EPS), phc = fmaxf(py2 - py1, EPS);
        float twc = fmaxf(tx2 - tx1, EPS), thc = fmaxf(ty2 - ty1, EPS);
        float dv = atanf(twc / thc) - atanf(pwc / phc);
        float v = (float)(4.0 / (M_PI * M_PI)) * dv * dv;
        float alpha = v / (1.0f - iou + v + EPS);
        r_ciou = iou - cdist / ediag - alpha * v;
    }
    if (lane == 0) {                                 // every wave writes its slot: no memset needed
        float* dst = objPart + (size_t)t * 8;
        ((float4*)dst)[0] = make_float4(r_ciou, r_obj, r_corr, r_cls);
        ((float4*)dst)[1] = make_float4(r_cnt, 0.f, 0.f, 0.f);
    }
}

// ---- finalize: sum 300 dense partials + 512 obj partials, emit scalar loss ----
__global__ void __launch_bounds__(256) yolo_fin(const double* __restrict__ densePart,
                                                const float* __restrict__ objPart,
                                                float* __restrict__ out) {
    double sp = 0, ciou = 0, obj = 0, corr = 0, cls = 0, cnt = 0;
    for (int i = threadIdx.x; i < N_DENSE_BLK; i += 256) sp += densePart[i];
    for (int t = threadIdx.x; t < NT; t += 256) {
        const float* p = objPart + (size_t)t * 8;
        ciou += p[0]; obj += p[1]; corr += p[2]; cls += p[3]; cnt += p[4];
    }
    #pragma unroll
    for (int off = 32; off > 0; off >>= 1) {
        sp   += __shfl_down(sp, off);   ciou += __shfl_down(ciou, off);
        obj  += __shfl_down(obj, off);  corr += __shfl_down(corr, off);
        cls  += __shfl_down(cls, off);  cnt  += __shfl_down(cnt, off);
    }
    __shared__ double sm[6][4];
    int wave = threadIdx.x >> 6, lane = threadIdx.x & 63;
    if (lane == 0) {
        sm[0][wave] = sp;  sm[1][wave] = ciou; sm[2][wave] = obj;
        sm[3][wave] = corr; sm[4][wave] = cls; sm[5][wave] = cnt;
    }
    __syncthreads();
    if (threadIdx.x == 0) {
        double T[6];
        for (int k = 0; k < 6; k++) T[k] = sm[k][0] + sm[k][1] + sm[k][2] + sm[k][3];
        double nobj = T[5];
        double noobj_sum = T[0] - T[3];              // total softplus - obj cells' softplus
        double d_obj = fmax(nobj, 1.0);
        double d_no  = fmax((double)CELLS - nobj, 1.0);
        double d_cls = fmax(nobj * (double)C, 1.0);
        double loss = (1.0 - T[1] / d_obj) + T[2] / d_obj
                    + 0.5 * (noobj_sum / d_no) + T[4] / d_cls;
        out[0] = (float)loss;
    }
}

extern "C" void kernel_launch(void* const* d_in, const int* in_sizes, int n_in,
                              void* d_out, int out_size, void* d_ws, size_t ws_size,
                              hipStream_t stream) {
    const float* preds   = (const float*)d_in[0];
    const float* anchors = (const float*)d_in[1];
    const int*   tcls    = (const int*)d_in[2];
    const float* tbox    = (const float*)d_in[3];

    double* densePart = (double*)d_ws;                      // [300]
    float*  objPart   = (float*)((char*)d_ws + OBJ_OFF);    // [512*8]

    yolo_fused<<<N_DENSE_BLK + N_OBJ_BLK, 256, 0, stream>>>(
        preds, anchors, tcls, tbox, densePart, objPart);
    yolo_fin<<<1, 256, 0, stream>>>(densePart, objPart, (float*)d_out);
}